// Round 8
// baseline (808.697 us; speedup 1.0000x reference)
//
#include <hip/hip_runtime.h>
#include <hip/hip_bf16.h>
#include <cstdint>
#include <cstddef>

#define DM   256
#define DI   512
#define DS   16
#define LSEQ 4096
#define BATCH 2
#define BLROWS (BATCH * LSEQ)   /* 8192 */
#define NCH  256                /* chunks per sequence */
#define CLEN 16                 /* steps per chunk */
#define NSC  16                 /* superchunks per sequence (16 chunks each) */
#define XCP  520                /* padded LDS row stride (u16) */

typedef __bf16 bf16x8 __attribute__((ext_vector_type(8)));
typedef float  f32x4  __attribute__((ext_vector_type(4)));
typedef unsigned short u16;
typedef unsigned int u32;
typedef u16 u16x8 __attribute__((ext_vector_type(8)));

__device__ __forceinline__ u16 f2bfu(float f) {
    union { float f; unsigned u; } c; c.f = f;
    unsigned u = c.u;
    return (u16)((u + 0x7fffu + ((u >> 16) & 1u)) >> 16);
}
__device__ __forceinline__ float bfu2f(u16 u) {
    union { unsigned u; float f; } c; c.u = ((unsigned)u) << 16; return c.f;
}
__device__ __forceinline__ float siluf(float v) {
    return v * (1.0f / (1.0f + __expf(-v)));
}
__device__ __forceinline__ void gload_lds16(const void* g, void* l) {
    __builtin_amdgcn_global_load_lds(
        (const __attribute__((address_space(1))) unsigned int*)g,
        (__attribute__((address_space(3))) unsigned int*)l, 16, 0, 0);
}

/* squaring-tree powers: an[n] = e1^(n+1), dep-depth 4 (R5/R6-verified) */
#define POW_TREE(an, e1)                                                     \
    {   float e2 = (e1)*(e1), e4 = e2*e2, e8 = e4*e4;                        \
        an[0]=(e1); an[1]=e2; an[2]=e2*(e1); an[3]=e4; an[4]=e4*(e1);        \
        an[5]=e4*e2; an[6]=e4*an[2]; an[7]=e8; an[8]=e8*(e1); an[9]=e8*e2;   \
        an[10]=e8*an[2]; an[11]=e8*e4; an[12]=e8*an[4]; an[13]=e8*an[5];     \
        an[14]=e8*an[6]; an[15]=e8*e8; }

/* ---------------- merged startup casts ---------------- */
#define N_INW  (2*1024*256)
#define N_OUTW (2*256*512)
#define N_XPW  (2*64*512)
#define N_Z    (BLROWS*DM)
__global__ __launch_bounds__(256) void cast_all_k(
    const float* __restrict__ in_w, const float* __restrict__ out_w,
    const float* __restrict__ xp_w, const float* __restrict__ z,
    u16* __restrict__ inw_bf, u16* __restrict__ outw_bf,
    u16* __restrict__ xpw_bf, u16* __restrict__ z_bf) {
    int i = blockIdx.x * 256 + threadIdx.x;
    if (i < N_INW) {
        inw_bf[i] = f2bfu(in_w[i]);
    } else if (i < N_INW + N_OUTW) {
        int j = i - N_INW;
        outw_bf[j] = f2bfu(out_w[j]);
    } else if (i < N_INW + N_OUTW + N_XPW) {
        int j = i - (N_INW + N_OUTW);
        int k = j & 511, o = (j >> 9) & 63, l = j >> 15;
        xpw_bf[j] = f2bfu((o < 48) ? xp_w[(l * 48 + o) * 512 + k] : 0.0f);
    } else {
        int j = i - (N_INW + N_OUTW + N_XPW);
        z_bf[j] = f2bfu(z[j]);
    }
}

/* ---------------- in_proj: LDS-staged bf16 MFMA GEMM (m97 pattern, R6) ------- */
__global__ __launch_bounds__(256) void gemm_in_k(
    const __bf16* __restrict__ A, const __bf16* __restrict__ B,
    u16* __restrict__ Cb, int M, int N, int K) {
    __shared__ __bf16 As[128 * 32];
    __shared__ __bf16 Bs[128 * 32];
    int tid = threadIdx.x, wave = tid >> 6, lane = tid & 63;
    int bm = blockIdx.x * 128, bn = blockIdx.y * 128;
    int wm = (wave & 1) * 64, wn = (wave >> 1) * 64;
    int row = lane & 15, q = lane >> 4;
    int srow = lane >> 2, sseg = lane & 3;
    f32x4 acc[4][4] = {};
    for (int k0 = 0; k0 < K; k0 += 32) {
        #pragma unroll
        for (int i = 0; i < 2; ++i) {
            int r0 = wave * 32 + i * 16;
            gload_lds16(A + (size_t)(bm + r0 + srow) * K + k0 + sseg * 8, As + r0 * 32);
            gload_lds16(B + (size_t)(bn + r0 + srow) * K + k0 + sseg * 8, Bs + r0 * 32);
        }
        __syncthreads();
        bf16x8 af[4], bfr[4];
        #pragma unroll
        for (int mi = 0; mi < 4; ++mi)
            af[mi] = *(const bf16x8*)&As[(wm + mi*16 + row) * 32 + q * 8];
        #pragma unroll
        for (int ni = 0; ni < 4; ++ni)
            bfr[ni] = *(const bf16x8*)&Bs[(wn + ni*16 + row) * 32 + q * 8];
        #pragma unroll
        for (int mi = 0; mi < 4; ++mi)
            #pragma unroll
            for (int ni = 0; ni < 4; ++ni)
                acc[mi][ni] = __builtin_amdgcn_mfma_f32_16x16x32_bf16(
                    af[mi], bfr[ni], acc[mi][ni], 0, 0, 0);
        __syncthreads();
    }
    #pragma unroll
    for (int mi = 0; mi < 4; ++mi)
        #pragma unroll
        for (int r = 0; r < 4; ++r) {
            size_t gr = (size_t)(bm + wm + mi*16 + q*4 + r) * N;
            #pragma unroll
            for (int ni = 0; ni < 4; ++ni)
                Cb[gr + bn + wn + ni*16 + row] = f2bfu(acc[mi][ni][r]);
        }
}

/* ---------------- fused A: conv+silu -> x_proj MFMA -> dt -> chunk scan ------- */
/* LDS-pipe-slim: all t-loop LDS broadcasts are ds_read_b128 (f32x4).          */
__global__ __launch_bounds__(512, 6) void fused_a_k(
    const u16* __restrict__ xz, const float* __restrict__ cw,
    const float* __restrict__ cb, const __bf16* __restrict__ xpw,
    const float* __restrict__ dtw, const float* __restrict__ dtb,
    const float* __restrict__ Alog,
    u32* __restrict__ dxc, float* __restrict__ BCg,
    u16* __restrict__ Pb, u16* __restrict__ Sb) {
    __shared__ u16 xc_s[CLEN * XCP];                       /* 16.6 KB */
    __shared__ __attribute__((aligned(16))) float xd_h[2][CLEN * 68];  /* 8.7 KB */
    int tid = threadIdx.x;
    int c = blockIdx.x, b = blockIdx.y;
    int flat = b * NCH + c;
    int bl0 = b * LSEQ + c * CLEN;
    int d = tid;

    /* phase 1: causal depthwise conv + bias + silu; xc kept in regs + LDS */
    u16 vb[CLEN];
    {
        float w0 = cw[d*4], w1 = cw[d*4+1], w2 = cw[d*4+2], w3 = cw[d*4+3];
        float bias = cb[d];
        float xm3 = 0.f, xm2 = 0.f, xm1 = 0.f;
        int l0 = c * CLEN;
        if (l0 - 3 >= 0) xm3 = bfu2f(xz[(size_t)(bl0 - 3) * 1024 + d]);
        if (l0 - 2 >= 0) xm2 = bfu2f(xz[(size_t)(bl0 - 2) * 1024 + d]);
        if (l0 - 1 >= 0) xm1 = bfu2f(xz[(size_t)(bl0 - 1) * 1024 + d]);
        #pragma unroll
        for (int t = 0; t < CLEN; ++t) {
            float xcur = bfu2f(xz[(size_t)(bl0 + t) * 1024 + d]);
            float acc = fmaf(w0, xm3, fmaf(w1, xm2, fmaf(w2, xm1, fmaf(w3, xcur, bias))));
            vb[t] = f2bfu(siluf(acc));
            xc_s[t * XCP + d] = vb[t];
            xm3 = xm2; xm2 = xm1; xm1 = xcur;
        }
    }
    __syncthreads();

    /* phase 2: x_proj  xd[16,64] = xc[16,512] @ xpw[64,512]^T (K-split 8 waves) */
    {
        int wave = tid >> 6, lane = tid & 63;
        int row = lane & 15, q = lane >> 4;
        int nt = wave & 3, kh = wave >> 2;
        f32x4 acc = {0.f, 0.f, 0.f, 0.f};
        #pragma unroll
        for (int kb = 0; kb < 8; ++kb) {
            int kk = (kh*8 + kb) * 32;
            bf16x8 a = *(const bf16x8*)&xc_s[row * XCP + kk + q*8];
            bf16x8 bb = *(const bf16x8*)(xpw + (size_t)(nt*16 + row) * 512 + kk + q*8);
            acc = __builtin_amdgcn_mfma_f32_16x16x32_bf16(a, bb, acc, 0, 0, 0);
        }
        #pragma unroll
        for (int r = 0; r < 4; ++r)
            xd_h[kh][(q*4 + r) * 68 + nt*16 + row] = acc[r];
    }
    __syncthreads();
    for (int j = tid; j < CLEN * 68; j += 512) xd_h[0][j] += xd_h[1][j];
    __syncthreads();

    /* store compact B,C (cols 16..47) for fused_c */
    {
        int t = tid >> 5, cc = tid & 31;
        BCg[(size_t)flat * (CLEN*32) + tid] = xd_h[0][t*68 + 16 + cc];
    }

    /* phase 3: dt = softplus(xd[:,:16] @ dtw^T + dtb); chunk scan -> P,S.
       All xd reads are f32x4 (row stride 68 f32 = 272 B, 16-aligned). */
    {
        f32x4 w0, w1, w2, w3;
        {
            const f32x4* w4 = (const f32x4*)(dtw + (size_t)d * 16);
            w0 = w4[0]; w1 = w4[1]; w2 = w4[2]; w3 = w4[3];
        }
        float dtbv = dtb[d];
        float Ac0; bool fastp = true;
        {
            const f32x4* a4 = (const f32x4*)(Alog + (size_t)d * 16);
            f32x4 v0 = a4[0];
            Ac0 = -__expf(v0[0]);
            #pragma unroll
            for (int g = 0; g < 4; ++g) { f32x4 v = a4[g];
                #pragma unroll
                for (int j = 0; j < 4; ++j) { int n = g*4 + j; if (n) {
                    float acn = -__expf(v[j]);
                    fastp = fastp && (fabsf(acn - (float)(n+1)*Ac0) <= 1e-4f*fabsf(acn));
                } } }
        }
        float s[16];
        #pragma unroll
        for (int n = 0; n < 16; ++n) s[n] = 0.f;
        float Sdt = 0.f;
        #pragma unroll
        for (int t = 0; t < CLEN; ++t) {
            const f32x4* xr = (const f32x4*)&xd_h[0][t * 68];
            f32x4 x0 = xr[0], x1 = xr[1], x2 = xr[2], x3 = xr[3];
            float acc = dtbv;
            #pragma unroll
            for (int j = 0; j < 4; ++j) {
                acc = fmaf(x0[j], w0[j], acc); acc = fmaf(x1[j], w1[j], acc);
                acc = fmaf(x2[j], w2[j], acc); acc = fmaf(x3[j], w3[j], acc);
            }
            float dtraw = (acc > 20.0f) ? acc : logf(1.0f + __expf(acc));
            u16 dtu = f2bfu(dtraw);
            float dtv = bfu2f(dtu);
            dxc[(size_t)(bl0 + t) * DI + d] = ((u32)dtu << 16) | (u32)vb[t];
            float xv = bfu2f(vb[t]);
            float dx = dtv * xv;
            Sdt += dtv;
            f32x4 b0 = xr[4], b1 = xr[5], b2 = xr[6], b3 = xr[7];
            float an[16];
            if (fastp) {
                float e1 = __expf(dtv * Ac0);
                POW_TREE(an, e1)
            } else {
                #pragma unroll
                for (int n = 0; n < 16; ++n)
                    an[n] = __expf(dtv * -__expf(Alog[(size_t)d*16 + n]));
            }
            #pragma unroll
            for (int j = 0; j < 4; ++j) {
                s[j]    = fmaf(an[j],    s[j],    b0[j] * dx);
                s[4+j]  = fmaf(an[4+j],  s[4+j],  b1[j] * dx);
                s[8+j]  = fmaf(an[8+j],  s[8+j],  b2[j] * dx);
                s[12+j] = fmaf(an[12+j], s[12+j], b3[j] * dx);
            }
        }
        float pw[16];
        if (fastp) {
            float E1 = __expf(Ac0 * Sdt);
            POW_TREE(pw, E1)
        } else {
            #pragma unroll
            for (int n = 0; n < 16; ++n)
                pw[n] = __expf(-__expf(Alog[(size_t)d*16 + n]) * Sdt);
        }
        size_t base = ((size_t)flat * DI + d) * 16;
        u16x8 pv0, pv1, sv0, sv1;
        #pragma unroll
        for (int n = 0; n < 8; ++n) {
            pv0[n] = f2bfu(pw[n]);  pv1[n] = f2bfu(pw[8+n]);
            sv0[n] = f2bfu(s[n]);   sv1[n] = f2bfu(s[8+n]);
        }
        *(u16x8*)(Pb + base)     = pv0;  *(u16x8*)(Pb + base + 8) = pv1;
        *(u16x8*)(Sb + base)     = sv0;  *(u16x8*)(Sb + base + 8) = sv1;
    }
}

/* ---------------- scan12: merged superchunk scan + entry states (R7-verified) */
__global__ __launch_bounds__(1024) void scan12_k(
    const u16* __restrict__ Pb, const u16* __restrict__ Sb,
    u16* __restrict__ Hg) {
    __shared__ float pag[NSC][64], sag[NSC][64];
    int tid = threadIdx.x;
    int eo = tid & 63, sc = tid >> 6;
    int elow = blockIdx.x * 64 + eo;
    int b = blockIdx.y;
    int cbase = b * NCH + sc * 16;
    float Pr[16], Sr[16];
    float h = 0.f, p = 1.f;
    #pragma unroll
    for (int k = 0; k < 16; ++k) {
        size_t a = (size_t)(cbase + k) * 8192 + elow;
        Pr[k] = bfu2f(Pb[a]); Sr[k] = bfu2f(Sb[a]);
        h = fmaf(Pr[k], h, Sr[k]);
        p *= Pr[k];
    }
    pag[sc][eo] = p; sag[sc][eo] = h;
    __syncthreads();
    float hs = 0.f;
    for (int s2 = 0; s2 < sc; ++s2)            /* sc uniform per wave */
        hs = fmaf(pag[s2][eo], hs, sag[s2][eo]);
    #pragma unroll
    for (int k = 0; k < 16; ++k) {
        size_t a = (size_t)(cbase + k) * 8192 + elow;
        Hg[a] = f2bfu(hs);
        hs = fmaf(Pr[k], hs, Sr[k]);
    }
}

/* ---------------- fused C: scan replay -> y slab (LDS) -> out_proj MFMA ------- */
__global__ __launch_bounds__(512, 6) void fused_c_k(
    const u32* __restrict__ dxc, const float* __restrict__ BCg,
    const u16* __restrict__ Hg,
    const float* __restrict__ Alog, const float* __restrict__ Dp,
    const u16* __restrict__ xz, const __bf16* __restrict__ outw,
    u16* __restrict__ Ob, float* __restrict__ Of) {
    __shared__ u16 y_s[CLEN * XCP];                        /* 16.6 KB */
    __shared__ __attribute__((aligned(16))) float BCs[CLEN * 32];   /* 2 KB */
    int tid = threadIdx.x;
    int c = blockIdx.x, b = blockIdx.y;
    int flat = b * NCH + c;
    int bl0 = b * LSEQ + c * CLEN;
    int d = tid;

    BCs[tid] = BCg[(size_t)flat * (CLEN*32) + tid];

    float Ac0; bool fastp = true;
    {
        const f32x4* a4 = (const f32x4*)(Alog + (size_t)d * 16);
        f32x4 v0 = a4[0];
        Ac0 = -__expf(v0[0]);
        #pragma unroll
        for (int g = 0; g < 4; ++g) { f32x4 v = a4[g];
            #pragma unroll
            for (int j = 0; j < 4; ++j) { int n = g*4 + j; if (n) {
                float acn = -__expf(v[j]);
                fastp = fastp && (fabsf(acn - (float)(n+1)*Ac0) <= 1e-4f*fabsf(acn));
            } } }
    }
    float h[16];
    {
        const u16* h8 = Hg + ((size_t)flat * DI + d) * 16;
        u16x8 hv0 = *(const u16x8*)h8;
        u16x8 hv1 = *(const u16x8*)(h8 + 8);
        #pragma unroll
        for (int n = 0; n < 8; ++n) { h[n] = bfu2f(hv0[n]); h[8+n] = bfu2f(hv1[n]); }
    }
    float Dv = Dp[d];
    __syncthreads();

    #pragma unroll
    for (int t = 0; t < CLEN; ++t) {
        u32 dxv = dxc[(size_t)(bl0 + t) * DI + d];
        float dtv = bfu2f((u16)(dxv >> 16));
        float xv  = bfu2f((u16)(dxv & 0xffffu));
        float gv  = bfu2f(xz[(size_t)(bl0 + t) * 1024 + DI + d]);
        float dx = dtv * xv;
        const f32x4* br = (const f32x4*)&BCs[t * 32];
        f32x4 b0 = br[0], b1 = br[1], b2 = br[2], b3 = br[3];
        f32x4 c0 = br[4], c1 = br[5], c2 = br[6], c3 = br[7];
        float an[16];
        if (fastp) {
            float e1 = __expf(dtv * Ac0);
            POW_TREE(an, e1)
        } else {
            #pragma unroll
            for (int n = 0; n < 16; ++n)
                an[n] = __expf(dtv * -__expf(Alog[(size_t)d*16 + n]));
        }
        float y0 = 0.f, y1 = 0.f, y2 = 0.f, y3 = 0.f;
        #pragma unroll
        for (int j = 0; j < 4; ++j) {
            h[j]    = fmaf(an[j],    h[j],    b0[j] * dx);
            h[4+j]  = fmaf(an[4+j],  h[4+j],  b1[j] * dx);
            h[8+j]  = fmaf(an[8+j],  h[8+j],  b2[j] * dx);
            h[12+j] = fmaf(an[12+j], h[12+j], b3[j] * dx);
            y0 = fmaf(h[j],    c0[j], y0);
            y1 = fmaf(h[4+j],  c1[j], y1);
            y2 = fmaf(h[8+j],  c2[j], y2);
            y3 = fmaf(h[12+j], c3[j], y3);
        }
        float y = (y0 + y1) + (y2 + y3);
        float yv = fmaf(xv, Dv, y) * siluf(gv);
        y_s[t * XCP + d] = f2bfu(yv);
    }
    __syncthreads();

    /* out_proj: O[16,256] = y_s[16,512] @ outw[256,512]^T; 8 waves x 2 N-tiles */
    {
        int wave = tid >> 6, lane = tid & 63;
        int row = lane & 15, q = lane >> 4;
        f32x4 acc[2] = {};
        #pragma unroll
        for (int kb = 0; kb < 16; ++kb) {
            bf16x8 a = *(const bf16x8*)&y_s[row * XCP + kb*32 + q*8];
            #pragma unroll
            for (int ni = 0; ni < 2; ++ni) {
                bf16x8 bb = *(const bf16x8*)(outw +
                    (size_t)(wave*32 + ni*16 + row) * 512 + kb*32 + q*8);
                acc[ni] = __builtin_amdgcn_mfma_f32_16x16x32_bf16(a, bb, acc[ni], 0, 0, 0);
            }
        }
        #pragma unroll
        for (int r = 0; r < 4; ++r) {
            size_t gr = (size_t)(bl0 + q*4 + r) * DM;
            #pragma unroll
            for (int ni = 0; ni < 2; ++ni) {
                int gc = wave*32 + ni*16 + row;
                if (Ob) Ob[gr + gc] = f2bfu(acc[ni][r]);
                else    Of[gr + gc] = acc[ni][r];
            }
        }
    }
}

/* ================================================================== */
extern "C" void kernel_launch(void* const* d_in, const int* in_sizes, int n_in,
                              void* d_out, int out_size, void* d_ws, size_t ws_size,
                              hipStream_t stream) {
    (void)in_sizes; (void)n_in; (void)out_size; (void)ws_size;
    const float* z_in   = (const float*)d_in[0];
    const float* in_w   = (const float*)d_in[1];
    const float* conv_w = (const float*)d_in[2];
    const float* conv_b = (const float*)d_in[3];
    const float* xp_w   = (const float*)d_in[4];
    const float* dt_w   = (const float*)d_in[5];
    const float* dt_b   = (const float*)d_in[6];
    const float* A_log  = (const float*)d_in[7];
    const float* D_par  = (const float*)d_in[8];
    const float* out_w  = (const float*)d_in[9];
    float* outp = (float*)d_out;

    char* p = (char*)d_ws;
    auto alloc = [&](size_t bytes) { char* r = p; p += (bytes + 255) & ~(size_t)255; return r; };
    u16* z_bf    = (u16*)alloc((size_t)BLROWS*DM*2);
    u16* z2_bf   = (u16*)alloc((size_t)BLROWS*DM*2);
    u16* xz_bf   = (u16*)alloc((size_t)BLROWS*1024*2);
    u32* dxc_bf  = (u32*)alloc((size_t)BLROWS*DI*4);
    u16* inw_bf  = (u16*)alloc((size_t)2*1024*256*2);
    u16* outw_bf = (u16*)alloc((size_t)2*256*512*2);
    u16* xpw_bf  = (u16*)alloc((size_t)2*64*512*2);
    float* BCg   = (float*)alloc((size_t)BATCH*NCH*CLEN*32*4);
    u16* Pbuf    = (u16*)alloc((size_t)BATCH*NCH*DI*DS*2);
    u16* Sbuf    = (u16*)alloc((size_t)BATCH*NCH*DI*DS*2);
    u16* Hbuf    = (u16*)alloc((size_t)BATCH*NCH*DI*DS*2);

    cast_all_k<<<(N_INW + N_OUTW + N_XPW + N_Z)/256, 256, 0, stream>>>(
        in_w, out_w, xp_w, z_in, inw_bf, outw_bf, xpw_bf, z_bf);

    const u16* zcur = z_bf;
    for (int l = 0; l < 2; ++l) {
        gemm_in_k<<<dim3(BLROWS/128, 1024/128), 256, 0, stream>>>(
            (const __bf16*)zcur, (const __bf16*)(inw_bf + (size_t)l*1024*256),
            xz_bf, BLROWS, 1024, 256);
        fused_a_k<<<dim3(NCH, BATCH), 512, 0, stream>>>(
            xz_bf, conv_w + (size_t)l*DI*4, conv_b + (size_t)l*DI,
            (const __bf16*)(xpw_bf + (size_t)l*64*512),
            dt_w + (size_t)l*DI*16, dt_b + (size_t)l*DI,
            A_log + (size_t)l*DI*DS,
            dxc_bf, BCg, Pbuf, Sbuf);
        scan12_k<<<dim3(8192/64, BATCH), 1024, 0, stream>>>(Pbuf, Sbuf, Hbuf);
        fused_c_k<<<dim3(NCH, BATCH), 512, 0, stream>>>(
            dxc_bf, BCg, Hbuf,
            A_log + (size_t)l*DI*DS, D_par + (size_t)l*DI,
            xz_bf, (const __bf16*)(outw_bf + (size_t)l*256*512),
            (l == 0) ? z2_bf : nullptr, (l == 1) ? outp : nullptr);
        zcur = z2_bf;
    }
}

// Round 9
// 508.651 us; speedup vs baseline: 1.5899x; 1.5899x over previous
//
#include <hip/hip_runtime.h>
#include <hip/hip_bf16.h>
#include <cstdint>
#include <cstddef>

#define DM   256
#define DI   512
#define DS   16
#define LSEQ 4096
#define BATCH 2
#define BLROWS (BATCH * LSEQ)   /* 8192 */
#define NCH  256                /* chunks per sequence */
#define CLEN 16                 /* steps per chunk */
#define NSC  16                 /* superchunks per sequence (16 chunks each) */
#define XCP  520                /* padded LDS row stride (u16) */
#define NBLK 512                /* fused_cs grid; 2 blocks/CU co-resident */

typedef __bf16 bf16x8 __attribute__((ext_vector_type(8)));
typedef float  f32x4  __attribute__((ext_vector_type(4)));
typedef unsigned short u16;
typedef unsigned int u32;
typedef u16 u16x8 __attribute__((ext_vector_type(8)));

__device__ __forceinline__ u16 f2bfu(float f) {
    union { float f; unsigned u; } c; c.f = f;
    unsigned u = c.u;
    return (u16)((u + 0x7fffu + ((u >> 16) & 1u)) >> 16);
}
__device__ __forceinline__ float bfu2f(u16 u) {
    union { unsigned u; float f; } c; c.u = ((unsigned)u) << 16; return c.f;
}
__device__ __forceinline__ float siluf(float v) {
    return v * (1.0f / (1.0f + __expf(-v)));
}
__device__ __forceinline__ void gload_lds16(const void* g, void* l) {
    __builtin_amdgcn_global_load_lds(
        (const __attribute__((address_space(1))) unsigned int*)g,
        (__attribute__((address_space(3))) unsigned int*)l, 16, 0, 0);
}

/* device-scope grid barrier, bounded spin (R2-verified pattern). */
__device__ __forceinline__ void gridbar(int* bar) {
    __syncthreads();
    if (threadIdx.x == 0) {
        __threadfence();
        atomicAdd(bar, 1);
        int it = 0;
        while (__hip_atomic_load(bar, __ATOMIC_RELAXED,
                                 __HIP_MEMORY_SCOPE_AGENT) < NBLK) {
            __builtin_amdgcn_s_sleep(8);
            if (++it > (1 << 22)) break;
        }
        __threadfence();
    }
    __syncthreads();
}

/* squaring-tree powers: an[n] = e1^(n+1), dep-depth 4 (R5/R6-verified) */
#define POW_TREE(an, e1)                                                     \
    {   float e2 = (e1)*(e1), e4 = e2*e2, e8 = e4*e4;                        \
        an[0]=(e1); an[1]=e2; an[2]=e2*(e1); an[3]=e4; an[4]=e4*(e1);        \
        an[5]=e4*e2; an[6]=e4*an[2]; an[7]=e8; an[8]=e8*(e1); an[9]=e8*e2;   \
        an[10]=e8*an[2]; an[11]=e8*e4; an[12]=e8*an[4]; an[13]=e8*an[5];     \
        an[14]=e8*an[6]; an[15]=e8*e8; }

/* ---------------- merged startup casts + barrier zeroing ---------------- */
#define N_INW  (2*1024*256)
#define N_OUTW (2*256*512)
#define N_XPW  (2*64*512)
#define N_Z    (BLROWS*DM)
__global__ __launch_bounds__(256) void cast_all_k(
    const float* __restrict__ in_w, const float* __restrict__ out_w,
    const float* __restrict__ xp_w, const float* __restrict__ z,
    u16* __restrict__ inw_bf, u16* __restrict__ outw_bf,
    u16* __restrict__ xpw_bf, u16* __restrict__ z_bf,
    int* __restrict__ bars) {
    if (blockIdx.x == 0 && threadIdx.x < 16) bars[threadIdx.x] = 0;
    int i = blockIdx.x * 256 + threadIdx.x;
    if (i < N_INW) {
        inw_bf[i] = f2bfu(in_w[i]);
    } else if (i < N_INW + N_OUTW) {
        int j = i - N_INW;
        outw_bf[j] = f2bfu(out_w[j]);
    } else if (i < N_INW + N_OUTW + N_XPW) {
        int j = i - (N_INW + N_OUTW);
        int k = j & 511, o = (j >> 9) & 63, l = j >> 15;
        xpw_bf[j] = f2bfu((o < 48) ? xp_w[(l * 48 + o) * 512 + k] : 0.0f);
    } else {
        int j = i - (N_INW + N_OUTW + N_XPW);
        z_bf[j] = f2bfu(z[j]);
    }
}

/* ---------------- in_proj: LDS-staged bf16 MFMA GEMM (m97 pattern, R6) ------- */
__global__ __launch_bounds__(256) void gemm_in_k(
    const __bf16* __restrict__ A, const __bf16* __restrict__ B,
    u16* __restrict__ Cb, int M, int N, int K) {
    __shared__ __bf16 As[128 * 32];
    __shared__ __bf16 Bs[128 * 32];
    int tid = threadIdx.x, wave = tid >> 6, lane = tid & 63;
    int bm = blockIdx.x * 128, bn = blockIdx.y * 128;
    int wm = (wave & 1) * 64, wn = (wave >> 1) * 64;
    int row = lane & 15, q = lane >> 4;
    int srow = lane >> 2, sseg = lane & 3;
    f32x4 acc[4][4] = {};
    for (int k0 = 0; k0 < K; k0 += 32) {
        #pragma unroll
        for (int i = 0; i < 2; ++i) {
            int r0 = wave * 32 + i * 16;
            gload_lds16(A + (size_t)(bm + r0 + srow) * K + k0 + sseg * 8, As + r0 * 32);
            gload_lds16(B + (size_t)(bn + r0 + srow) * K + k0 + sseg * 8, Bs + r0 * 32);
        }
        __syncthreads();
        bf16x8 af[4], bfr[4];
        #pragma unroll
        for (int mi = 0; mi < 4; ++mi)
            af[mi] = *(const bf16x8*)&As[(wm + mi*16 + row) * 32 + q * 8];
        #pragma unroll
        for (int ni = 0; ni < 4; ++ni)
            bfr[ni] = *(const bf16x8*)&Bs[(wn + ni*16 + row) * 32 + q * 8];
        #pragma unroll
        for (int mi = 0; mi < 4; ++mi)
            #pragma unroll
            for (int ni = 0; ni < 4; ++ni)
                acc[mi][ni] = __builtin_amdgcn_mfma_f32_16x16x32_bf16(
                    af[mi], bfr[ni], acc[mi][ni], 0, 0, 0);
        __syncthreads();
    }
    #pragma unroll
    for (int mi = 0; mi < 4; ++mi)
        #pragma unroll
        for (int r = 0; r < 4; ++r) {
            size_t gr = (size_t)(bm + wm + mi*16 + q*4 + r) * N;
            #pragma unroll
            for (int ni = 0; ni < 4; ++ni)
                Cb[gr + bn + wn + ni*16 + row] = f2bfu(acc[mi][ni][r]);
        }
}

/* ---------------- fused A: conv+silu -> x_proj MFMA -> dt -> chunk scan ------- */
/* R6 body verbatim; outputs packed dt|xc (u32).                                */
__global__ __launch_bounds__(512, 6) void fused_a_k(
    const u16* __restrict__ xz, const float* __restrict__ cw,
    const float* __restrict__ cb, const __bf16* __restrict__ xpw,
    const float* __restrict__ dtw, const float* __restrict__ dtb,
    const float* __restrict__ Alog,
    u32* __restrict__ dxc, float* __restrict__ BCg,
    u16* __restrict__ Pb, u16* __restrict__ Sb) {
    __shared__ u16 xc_s[CLEN * XCP];       /* 16.6 KB */
    __shared__ float xd_h[2][CLEN * 68];   /* 8.7 KB */
    int tid = threadIdx.x;
    int c = blockIdx.x, b = blockIdx.y;
    int flat = b * NCH + c;
    int bl0 = b * LSEQ + c * CLEN;
    int d = tid;

    /* phase 1: causal depthwise conv + bias + silu (thread = channel) */
    u16 vb[CLEN];
    {
        float w0 = cw[d*4], w1 = cw[d*4+1], w2 = cw[d*4+2], w3 = cw[d*4+3];
        float bias = cb[d];
        float xm3 = 0.f, xm2 = 0.f, xm1 = 0.f;
        int l0 = c * CLEN;
        if (l0 - 3 >= 0) xm3 = bfu2f(xz[(size_t)(bl0 - 3) * 1024 + d]);
        if (l0 - 2 >= 0) xm2 = bfu2f(xz[(size_t)(bl0 - 2) * 1024 + d]);
        if (l0 - 1 >= 0) xm1 = bfu2f(xz[(size_t)(bl0 - 1) * 1024 + d]);
        #pragma unroll 4
        for (int t = 0; t < CLEN; ++t) {
            float xcur = bfu2f(xz[(size_t)(bl0 + t) * 1024 + d]);
            float acc = fmaf(w0, xm3, fmaf(w1, xm2, fmaf(w2, xm1, fmaf(w3, xcur, bias))));
            vb[t] = f2bfu(siluf(acc));
            xc_s[t * XCP + d] = vb[t];
            xm3 = xm2; xm2 = xm1; xm1 = xcur;
        }
    }
    __syncthreads();

    /* phase 2: x_proj  xd[16,64] = xc[16,512] @ xpw[64,512]^T (K-split 8 waves) */
    {
        int wave = tid >> 6, lane = tid & 63;
        int row = lane & 15, q = lane >> 4;
        int nt = wave & 3, kh = wave >> 2;
        f32x4 acc = {0.f, 0.f, 0.f, 0.f};
        #pragma unroll
        for (int kb = 0; kb < 8; ++kb) {
            int kk = (kh*8 + kb) * 32;
            bf16x8 a = *(const bf16x8*)&xc_s[row * XCP + kk + q*8];
            bf16x8 bb = *(const bf16x8*)(xpw + (size_t)(nt*16 + row) * 512 + kk + q*8);
            acc = __builtin_amdgcn_mfma_f32_16x16x32_bf16(a, bb, acc, 0, 0, 0);
        }
        #pragma unroll
        for (int r = 0; r < 4; ++r)
            xd_h[kh][(q*4 + r) * 68 + nt*16 + row] = acc[r];
    }
    __syncthreads();
    for (int j = tid; j < CLEN * 68; j += 512) xd_h[0][j] += xd_h[1][j];
    __syncthreads();

    /* store compact B,C (cols 16..47) for fused_cs */
    {
        int t = tid >> 5, cc = tid & 31;
        BCg[(size_t)flat * (CLEN*32) + tid] = xd_h[0][t*68 + 16 + cc];
    }

    /* phase 3: dt = softplus(xd[:,:16] @ dtw^T + dtb); chunk scan -> P,S */
    {
        float dtwr[16];
        const f32x4* w4 = (const f32x4*)(dtw + (size_t)d * 16);
        #pragma unroll
        for (int g = 0; g < 4; ++g) { f32x4 v = w4[g];
            dtwr[g*4] = v[0]; dtwr[g*4+1] = v[1]; dtwr[g*4+2] = v[2]; dtwr[g*4+3] = v[3]; }
        float dtbv = dtb[d];
        float Ac0; bool fastp = true;
        {
            const f32x4* a4 = (const f32x4*)(Alog + (size_t)d * 16);
            f32x4 v0 = a4[0];
            Ac0 = -__expf(v0[0]);
            #pragma unroll
            for (int g = 0; g < 4; ++g) { f32x4 v = a4[g];
                #pragma unroll
                for (int j = 0; j < 4; ++j) { int n = g*4 + j; if (n) {
                    float acn = -__expf(v[j]);
                    fastp = fastp && (fabsf(acn - (float)(n+1)*Ac0) <= 1e-4f*fabsf(acn));
                } } }
        }
        float s[16];
        #pragma unroll
        for (int n = 0; n < 16; ++n) s[n] = 0.f;
        float Sdt = 0.f;
        if (fastp) {
            for (int t = 0; t < CLEN; ++t) {
                float acc = dtbv;
                #pragma unroll
                for (int r = 0; r < 16; ++r) acc = fmaf(xd_h[0][t*68 + r], dtwr[r], acc);
                float dtraw = (acc > 20.0f) ? acc : logf(1.0f + __expf(acc));
                u16 dtu = f2bfu(dtraw);
                dxc[(size_t)(bl0 + t) * DI + d] = ((u32)dtu << 16) | (u32)vb[t];
                float dtv = bfu2f(dtu);
                float xv = bfu2f(vb[t]);
                float dx = dtv * xv;
                Sdt += dtv;
                float e1 = __expf(dtv * Ac0);
                float an[16];
                POW_TREE(an, e1)
                #pragma unroll
                for (int n = 0; n < 16; ++n)
                    s[n] = fmaf(an[n], s[n], xd_h[0][t*68 + 16 + n] * dx);
            }
        } else {
            for (int t = 0; t < CLEN; ++t) {
                float acc = dtbv;
                #pragma unroll
                for (int r = 0; r < 16; ++r) acc = fmaf(xd_h[0][t*68 + r], dtwr[r], acc);
                float dtraw = (acc > 20.0f) ? acc : logf(1.0f + __expf(acc));
                u16 dtu = f2bfu(dtraw);
                dxc[(size_t)(bl0 + t) * DI + d] = ((u32)dtu << 16) | (u32)vb[t];
                float dtv = bfu2f(dtu);
                float xv = bfu2f(vb[t]);
                float dx = dtv * xv;
                Sdt += dtv;
                #pragma unroll
                for (int n = 0; n < 16; ++n) {
                    float an = __expf(dtv * -__expf(Alog[(size_t)d*16 + n]));
                    s[n] = fmaf(an, s[n], xd_h[0][t*68 + 16 + n] * dx);
                }
            }
        }
        float pw[16];
        if (fastp) {
            float E1 = __expf(Ac0 * Sdt);
            POW_TREE(pw, E1)
        } else {
            #pragma unroll
            for (int n = 0; n < 16; ++n)
                pw[n] = __expf(-__expf(Alog[(size_t)d*16 + n]) * Sdt);
        }
        size_t base = ((size_t)flat * DI + d) * 16;
        u16x8 pv0, pv1, sv0, sv1;
        #pragma unroll
        for (int n = 0; n < 8; ++n) {
            pv0[n] = f2bfu(pw[n]);  pv1[n] = f2bfu(pw[8+n]);
            sv0[n] = f2bfu(s[n]);   sv1[n] = f2bfu(s[8+n]);
        }
        *(u16x8*)(Pb + base)     = pv0;  *(u16x8*)(Pb + base + 8) = pv1;
        *(u16x8*)(Sb + base)     = sv0;  *(u16x8*)(Sb + base + 8) = sv1;
    }
}

/* ---------------- fused CS: scan (2 gridbars) + replay + out_proj ------------ */
/* grid (NCH, BATCH) = 512 blocks x 512 thr, 2 blocks/CU co-resident.          */
__global__ __launch_bounds__(512, 4) void fused_cs_k(
    const u16* __restrict__ Pb, const u16* __restrict__ Sb,
    float* __restrict__ Pagg, float* __restrict__ Sagg,
    u16* __restrict__ Hg,
    const u32* __restrict__ dxc, const float* __restrict__ BCg,
    const float* __restrict__ Alog, const float* __restrict__ Dp,
    const u16* __restrict__ xz, const __bf16* __restrict__ outw,
    int* __restrict__ bars,
    u16* __restrict__ Ob, float* __restrict__ Of) {
    __shared__ u16 y_s[CLEN * XCP];        /* 16.6 KB */
    __shared__ float BCs[CLEN * 32];       /* 2 KB */
    int tid = threadIdx.x;
    int c = blockIdx.x, b = blockIdx.y;
    int flat = b * NCH + c;
    int bl0 = b * LSEQ + c * CLEN;
    int d = tid;

    BCs[tid] = BCg[(size_t)flat * (CLEN*32) + tid];

    float Ac0; bool fastp = true;
    {
        const f32x4* a4 = (const f32x4*)(Alog + (size_t)d * 16);
        f32x4 v0 = a4[0];
        Ac0 = -__expf(v0[0]);
        #pragma unroll
        for (int g = 0; g < 4; ++g) { f32x4 v = a4[g];
            #pragma unroll
            for (int j = 0; j < 4; ++j) { int n = g*4 + j; if (n) {
                float acn = -__expf(v[j]);
                fastp = fastp && (fabsf(acn - (float)(n+1)*Ac0) <= 1e-4f*fabsf(acn));
            } } }
    }
    float Dv = Dp[d];

    /* scan phase A: superchunk-local scan; P/S held in regs across bar */
    int gid = flat * 512 + tid;
    int b2 = gid >> 17;
    int rem = gid & 131071;
    int sc = rem >> 13, elow = rem & 8191;     /* sc, b2 uniform per block */
    int cbase = b2 * NCH + sc * 16;
    float Pr[16], Sr[16];
    {
        float h2 = 0.f, pp = 1.f;
        #pragma unroll
        for (int k = 0; k < 16; ++k) {
            size_t a = (size_t)(cbase + k) * 8192 + elow;
            Pr[k] = bfu2f(Pb[a]); Sr[k] = bfu2f(Sb[a]);
            h2 = fmaf(Pr[k], h2, Sr[k]);
            pp *= Pr[k];
        }
        size_t ai = (size_t)(b2*NSC + sc) * 8192 + elow;
        Pagg[ai] = pp;
        Sagg[ai] = h2;
    }

    gridbar(&bars[0]);

    /* scan phase B: aggregate prefix + per-chunk entry states (bf16 Hg) */
    {
        float hs = 0.f;
        for (int s2 = 0; s2 < sc; ++s2) {
            size_t ai = (size_t)(b2*NSC + s2) * 8192 + elow;
            hs = fmaf(Pagg[ai], hs, Sagg[ai]);
        }
        #pragma unroll
        for (int k = 0; k < 16; ++k) {
            size_t a = (size_t)(cbase + k) * 8192 + elow;
            Hg[a] = f2bfu(hs);
            hs = fmaf(Pr[k], hs, Sr[k]);
        }
    }

    gridbar(&bars[1]);

    /* replay with entry state -> y (R6 body, packed dxc loads) */
    float h[16];
    {
        const u16* h8 = Hg + ((size_t)flat * DI + d) * 16;
        u16x8 hv0 = *(const u16x8*)h8;
        u16x8 hv1 = *(const u16x8*)(h8 + 8);
        #pragma unroll
        for (int n = 0; n < 8; ++n) { h[n] = bfu2f(hv0[n]); h[8+n] = bfu2f(hv1[n]); }
    }

    if (fastp) {
        for (int t = 0; t < CLEN; ++t) {
            u32 dxv = dxc[(size_t)(bl0 + t) * DI + d];
            float dtv = bfu2f((u16)(dxv >> 16));
            float xv  = bfu2f((u16)(dxv & 0xffffu));
            float gv  = bfu2f(xz[(size_t)(bl0 + t) * 1024 + DI + d]);
            float dx = dtv * xv;
            float e1 = __expf(dtv * Ac0);
            float an[16];
            POW_TREE(an, e1)
            float y0 = 0.f, y1 = 0.f, y2 = 0.f, y3 = 0.f;
            #pragma unroll
            for (int n = 0; n < 4; ++n) {
                h[n]    = fmaf(an[n],    h[n],    BCs[t*32 + n]    * dx);
                h[4+n]  = fmaf(an[4+n],  h[4+n],  BCs[t*32 + 4+n]  * dx);
                h[8+n]  = fmaf(an[8+n],  h[8+n],  BCs[t*32 + 8+n]  * dx);
                h[12+n] = fmaf(an[12+n], h[12+n], BCs[t*32 + 12+n] * dx);
                y0 = fmaf(h[n],    BCs[t*32 + 16 + n],    y0);
                y1 = fmaf(h[4+n],  BCs[t*32 + 16 + 4+n],  y1);
                y2 = fmaf(h[8+n],  BCs[t*32 + 16 + 8+n],  y2);
                y3 = fmaf(h[12+n], BCs[t*32 + 16 + 12+n], y3);
            }
            float y = (y0 + y1) + (y2 + y3);
            float yv = fmaf(xv, Dv, y) * siluf(gv);
            y_s[t * XCP + d] = f2bfu(yv);
        }
    } else {
        for (int t = 0; t < CLEN; ++t) {
            u32 dxv = dxc[(size_t)(bl0 + t) * DI + d];
            float dtv = bfu2f((u16)(dxv >> 16));
            float xv  = bfu2f((u16)(dxv & 0xffffu));
            float gv  = bfu2f(xz[(size_t)(bl0 + t) * 1024 + DI + d]);
            float dx = dtv * xv;
            float y = 0.f;
            #pragma unroll
            for (int n = 0; n < 16; ++n) {
                float an = __expf(dtv * -__expf(Alog[(size_t)d*16 + n]));
                h[n] = fmaf(an, h[n], BCs[t*32 + n] * dx);
                y = fmaf(h[n], BCs[t*32 + 16 + n], y);
            }
            float yv = fmaf(xv, Dv, y) * siluf(gv);
            y_s[t * XCP + d] = f2bfu(yv);
        }
    }
    __syncthreads();

    /* out_proj: O[16,256] = y_s[16,512] @ outw[256,512]^T; 8 waves x 2 N-tiles */
    {
        int wave = tid >> 6, lane = tid & 63;
        int row = lane & 15, q = lane >> 4;
        f32x4 acc[2] = {};
        #pragma unroll
        for (int kb = 0; kb < 16; ++kb) {
            bf16x8 a = *(const bf16x8*)&y_s[row * XCP + kb*32 + q*8];
            #pragma unroll
            for (int ni = 0; ni < 2; ++ni) {
                bf16x8 bb = *(const bf16x8*)(outw +
                    (size_t)(wave*32 + ni*16 + row) * 512 + kb*32 + q*8);
                acc[ni] = __builtin_amdgcn_mfma_f32_16x16x32_bf16(a, bb, acc[ni], 0, 0, 0);
            }
        }
        #pragma unroll
        for (int r = 0; r < 4; ++r) {
            size_t gr = (size_t)(bl0 + q*4 + r) * DM;
            #pragma unroll
            for (int ni = 0; ni < 2; ++ni) {
                int gc = wave*32 + ni*16 + row;
                if (Ob) Ob[gr + gc] = f2bfu(acc[ni][r]);
                else    Of[gr + gc] = acc[ni][r];
            }
        }
    }
}

/* ================================================================== */
extern "C" void kernel_launch(void* const* d_in, const int* in_sizes, int n_in,
                              void* d_out, int out_size, void* d_ws, size_t ws_size,
                              hipStream_t stream) {
    (void)in_sizes; (void)n_in; (void)out_size; (void)ws_size;
    const float* z_in   = (const float*)d_in[0];
    const float* in_w   = (const float*)d_in[1];
    const float* conv_w = (const float*)d_in[2];
    const float* conv_b = (const float*)d_in[3];
    const float* xp_w   = (const float*)d_in[4];
    const float* dt_w   = (const float*)d_in[5];
    const float* dt_b   = (const float*)d_in[6];
    const float* A_log  = (const float*)d_in[7];
    const float* D_par  = (const float*)d_in[8];
    const float* out_w  = (const float*)d_in[9];
    float* outp = (float*)d_out;

    char* p = (char*)d_ws;
    auto alloc = [&](size_t bytes) { char* r = p; p += (bytes + 255) & ~(size_t)255; return r; };
    u16* z_bf    = (u16*)alloc((size_t)BLROWS*DM*2);
    u16* z2_bf   = (u16*)alloc((size_t)BLROWS*DM*2);
    u16* xz_bf   = (u16*)alloc((size_t)BLROWS*1024*2);
    u32* dxc_bf  = (u32*)alloc((size_t)BLROWS*DI*4);
    u16* inw_bf  = (u16*)alloc((size_t)2*1024*256*2);
    u16* outw_bf = (u16*)alloc((size_t)2*256*512*2);
    u16* xpw_bf  = (u16*)alloc((size_t)2*64*512*2);
    float* BCg   = (float*)alloc((size_t)BATCH*NCH*CLEN*32*4);
    u16* Pbuf    = (u16*)alloc((size_t)BATCH*NCH*DI*DS*2);
    u16* Sbuf    = (u16*)alloc((size_t)BATCH*NCH*DI*DS*2);
    u16* Hbuf    = (u16*)alloc((size_t)BATCH*NCH*DI*DS*2);
    float* PaggG = (float*)alloc((size_t)BATCH*NSC*8192*4);
    float* SaggG = (float*)alloc((size_t)BATCH*NSC*8192*4);
    int* bars    = (int*)alloc(64);

    cast_all_k<<<(N_INW + N_OUTW + N_XPW + N_Z)/256, 256, 0, stream>>>(
        in_w, out_w, xp_w, z_in, inw_bf, outw_bf, xpw_bf, z_bf, bars);

    const u16* zcur = z_bf;
    for (int l = 0; l < 2; ++l) {
        gemm_in_k<<<dim3(BLROWS/128, 1024/128), 256, 0, stream>>>(
            (const __bf16*)zcur, (const __bf16*)(inw_bf + (size_t)l*1024*256),
            xz_bf, BLROWS, 1024, 256);
        fused_a_k<<<dim3(NCH, BATCH), 512, 0, stream>>>(
            xz_bf, conv_w + (size_t)l*DI*4, conv_b + (size_t)l*DI,
            (const __bf16*)(xpw_bf + (size_t)l*64*512),
            dt_w + (size_t)l*DI*16, dt_b + (size_t)l*DI,
            A_log + (size_t)l*DI*DS,
            dxc_bf, BCg, Pbuf, Sbuf);
        fused_cs_k<<<dim3(NCH, BATCH), 512, 0, stream>>>(
            Pbuf, Sbuf, PaggG, SaggG, Hbuf,
            dxc_bf, BCg,
            A_log + (size_t)l*DI*DS, D_par + (size_t)l*DI,
            xz_bf, (const __bf16*)(outw_bf + (size_t)l*256*512),
            bars + (size_t)l*2,
            (l == 0) ? z2_bf : nullptr, (l == 1) ? outp : nullptr);
        zcur = z2_bf;
    }
}

// Round 10
// 308.733 us; speedup vs baseline: 2.6194x; 1.6475x over previous
//
#include <hip/hip_runtime.h>
#include <hip/hip_bf16.h>
#include <cstdint>
#include <cstddef>

#define DM   256
#define DI   512
#define DS   16
#define LSEQ 4096
#define BATCH 2
#define BLROWS (BATCH * LSEQ)   /* 8192 */
#define NCH  256                /* chunks per sequence */
#define CLEN 16                 /* steps per chunk */
#define NSC  16                 /* superchunks per sequence (16 chunks each) */
#define XCP  520                /* padded LDS row stride (u16) */

typedef __bf16 bf16x8 __attribute__((ext_vector_type(8)));
typedef float  f32x4  __attribute__((ext_vector_type(4)));
typedef unsigned short u16;
typedef unsigned int u32;
typedef u16 u16x8 __attribute__((ext_vector_type(8)));

__device__ __forceinline__ u16 f2bfu(float f) {
    union { float f; unsigned u; } c; c.f = f;
    unsigned u = c.u;
    return (u16)((u + 0x7fffu + ((u >> 16) & 1u)) >> 16);
}
__device__ __forceinline__ float bfu2f(u16 u) {
    union { unsigned u; float f; } c; c.u = ((unsigned)u) << 16; return c.f;
}
__device__ __forceinline__ float siluf(float v) {
    return v * (1.0f / (1.0f + __expf(-v)));
}
__device__ __forceinline__ void gload_lds16(const void* g, void* l) {
    __builtin_amdgcn_global_load_lds(
        (const __attribute__((address_space(1))) unsigned int*)g,
        (__attribute__((address_space(3))) unsigned int*)l, 16, 0, 0);
}

/* squaring-tree powers: an[n] = e1^(n+1), dep-depth 4 (R5/R6-verified) */
#define POW_TREE(an, e1)                                                     \
    {   float e2 = (e1)*(e1), e4 = e2*e2, e8 = e4*e4;                        \
        an[0]=(e1); an[1]=e2; an[2]=e2*(e1); an[3]=e4; an[4]=e4*(e1);        \
        an[5]=e4*e2; an[6]=e4*an[2]; an[7]=e8; an[8]=e8*(e1); an[9]=e8*e2;   \
        an[10]=e8*an[2]; an[11]=e8*e4; an[12]=e8*an[4]; an[13]=e8*an[5];     \
        an[14]=e8*an[6]; an[15]=e8*e8; }

/* ---------------- merged startup casts ---------------- */
#define N_INW  (2*1024*256)
#define N_OUTW (2*256*512)
#define N_XPW  (2*64*512)
#define N_Z    (BLROWS*DM)
__global__ __launch_bounds__(256) void cast_all_k(
    const float* __restrict__ in_w, const float* __restrict__ out_w,
    const float* __restrict__ xp_w, const float* __restrict__ z,
    u16* __restrict__ inw_bf, u16* __restrict__ outw_bf,
    u16* __restrict__ xpw_bf, u16* __restrict__ z_bf) {
    int i = blockIdx.x * 256 + threadIdx.x;
    if (i < N_INW) {
        inw_bf[i] = f2bfu(in_w[i]);
    } else if (i < N_INW + N_OUTW) {
        int j = i - N_INW;
        outw_bf[j] = f2bfu(out_w[j]);
    } else if (i < N_INW + N_OUTW + N_XPW) {
        int j = i - (N_INW + N_OUTW);
        int k = j & 511, o = (j >> 9) & 63, l = j >> 15;
        xpw_bf[j] = f2bfu((o < 48) ? xp_w[(l * 48 + o) * 512 + k] : 0.0f);
    } else {
        int j = i - (N_INW + N_OUTW + N_XPW);
        z_bf[j] = f2bfu(z[j]);
    }
}

/* ---------------- in_proj: LDS-staged bf16 MFMA GEMM (m97 pattern, R6) ------- */
__global__ __launch_bounds__(256) void gemm_in_k(
    const __bf16* __restrict__ A, const __bf16* __restrict__ B,
    u16* __restrict__ Cb, int M, int N, int K) {
    __shared__ __bf16 As[128 * 32];
    __shared__ __bf16 Bs[128 * 32];
    int tid = threadIdx.x, wave = tid >> 6, lane = tid & 63;
    int bm = blockIdx.x * 128, bn = blockIdx.y * 128;
    int wm = (wave & 1) * 64, wn = (wave >> 1) * 64;
    int row = lane & 15, q = lane >> 4;
    int srow = lane >> 2, sseg = lane & 3;
    f32x4 acc[4][4] = {};
    for (int k0 = 0; k0 < K; k0 += 32) {
        #pragma unroll
        for (int i = 0; i < 2; ++i) {
            int r0 = wave * 32 + i * 16;
            gload_lds16(A + (size_t)(bm + r0 + srow) * K + k0 + sseg * 8, As + r0 * 32);
            gload_lds16(B + (size_t)(bn + r0 + srow) * K + k0 + sseg * 8, Bs + r0 * 32);
        }
        __syncthreads();
        bf16x8 af[4], bfr[4];
        #pragma unroll
        for (int mi = 0; mi < 4; ++mi)
            af[mi] = *(const bf16x8*)&As[(wm + mi*16 + row) * 32 + q * 8];
        #pragma unroll
        for (int ni = 0; ni < 4; ++ni)
            bfr[ni] = *(const bf16x8*)&Bs[(wn + ni*16 + row) * 32 + q * 8];
        #pragma unroll
        for (int mi = 0; mi < 4; ++mi)
            #pragma unroll
            for (int ni = 0; ni < 4; ++ni)
                acc[mi][ni] = __builtin_amdgcn_mfma_f32_16x16x32_bf16(
                    af[mi], bfr[ni], acc[mi][ni], 0, 0, 0);
        __syncthreads();
    }
    #pragma unroll
    for (int mi = 0; mi < 4; ++mi)
        #pragma unroll
        for (int r = 0; r < 4; ++r) {
            size_t gr = (size_t)(bm + wm + mi*16 + q*4 + r) * N;
            #pragma unroll
            for (int ni = 0; ni < 4; ++ni)
                Cb[gr + bn + wn + ni*16 + row] = f2bfu(acc[mi][ni][r]);
        }
}

/* ---------------- fused A: conv+silu -> x_proj MFMA -> dt -> chunk scan ------- */
/* R6 structure; phase-3 LDS reads vectorized to ds_read_b128 (t-loop NOT
   unrolled, to avoid R8's spill).  Output dt|xc packed u32.                    */
__global__ __launch_bounds__(512, 4) void fused_a_k(
    const u16* __restrict__ xz, const float* __restrict__ cw,
    const float* __restrict__ cb, const __bf16* __restrict__ xpw,
    const float* __restrict__ dtw, const float* __restrict__ dtb,
    const float* __restrict__ Alog,
    u32* __restrict__ dxc, float* __restrict__ BCg,
    u16* __restrict__ Pb, u16* __restrict__ Sb) {
    __shared__ u16 xc_s[CLEN * XCP];                                   /* 16.6 KB */
    __shared__ __attribute__((aligned(16))) float xd_h[2][CLEN * 68];  /* 8.7 KB */
    int tid = threadIdx.x;
    int c = blockIdx.x, b = blockIdx.y;
    int flat = b * NCH + c;
    int bl0 = b * LSEQ + c * CLEN;
    int d = tid;

    /* phase 1: causal depthwise conv + bias + silu (thread = channel) */
    u16 vb[CLEN];
    {
        float w0 = cw[d*4], w1 = cw[d*4+1], w2 = cw[d*4+2], w3 = cw[d*4+3];
        float bias = cb[d];
        float xm3 = 0.f, xm2 = 0.f, xm1 = 0.f;
        int l0 = c * CLEN;
        if (l0 - 3 >= 0) xm3 = bfu2f(xz[(size_t)(bl0 - 3) * 1024 + d]);
        if (l0 - 2 >= 0) xm2 = bfu2f(xz[(size_t)(bl0 - 2) * 1024 + d]);
        if (l0 - 1 >= 0) xm1 = bfu2f(xz[(size_t)(bl0 - 1) * 1024 + d]);
        #pragma unroll 4
        for (int t = 0; t < CLEN; ++t) {
            float xcur = bfu2f(xz[(size_t)(bl0 + t) * 1024 + d]);
            float acc = fmaf(w0, xm3, fmaf(w1, xm2, fmaf(w2, xm1, fmaf(w3, xcur, bias))));
            vb[t] = f2bfu(siluf(acc));
            xc_s[t * XCP + d] = vb[t];
            xm3 = xm2; xm2 = xm1; xm1 = xcur;
        }
    }
    __syncthreads();

    /* phase 2: x_proj  xd[16,64] = xc[16,512] @ xpw[64,512]^T (K-split 8 waves) */
    {
        int wave = tid >> 6, lane = tid & 63;
        int row = lane & 15, q = lane >> 4;
        int nt = wave & 3, kh = wave >> 2;
        f32x4 acc = {0.f, 0.f, 0.f, 0.f};
        #pragma unroll
        for (int kb = 0; kb < 8; ++kb) {
            int kk = (kh*8 + kb) * 32;
            bf16x8 a = *(const bf16x8*)&xc_s[row * XCP + kk + q*8];
            bf16x8 bb = *(const bf16x8*)(xpw + (size_t)(nt*16 + row) * 512 + kk + q*8);
            acc = __builtin_amdgcn_mfma_f32_16x16x32_bf16(a, bb, acc, 0, 0, 0);
        }
        #pragma unroll
        for (int r = 0; r < 4; ++r)
            xd_h[kh][(q*4 + r) * 68 + nt*16 + row] = acc[r];
    }
    __syncthreads();
    for (int j = tid; j < CLEN * 68; j += 512) xd_h[0][j] += xd_h[1][j];
    __syncthreads();

    /* store compact B,C (cols 16..47) for fused_c */
    {
        int t = tid >> 5, cc = tid & 31;
        BCg[(size_t)flat * (CLEN*32) + tid] = xd_h[0][t*68 + 16 + cc];
    }

    /* phase 3: dt = softplus(xd[:,:16] @ dtw^T + dtb); chunk scan -> P,S.
       LDS reads as f32x4 (rows 272 B, offsets 16-aligned). */
    {
        f32x4 dw0, dw1, dw2, dw3;
        {
            const f32x4* w4 = (const f32x4*)(dtw + (size_t)d * 16);
            dw0 = w4[0]; dw1 = w4[1]; dw2 = w4[2]; dw3 = w4[3];
        }
        float dtbv = dtb[d];
        float Ac0; bool fastp = true;
        {
            const f32x4* a4 = (const f32x4*)(Alog + (size_t)d * 16);
            f32x4 v0 = a4[0];
            Ac0 = -__expf(v0[0]);
            #pragma unroll
            for (int g = 0; g < 4; ++g) { f32x4 v = a4[g];
                #pragma unroll
                for (int j = 0; j < 4; ++j) { int n = g*4 + j; if (n) {
                    float acn = -__expf(v[j]);
                    fastp = fastp && (fabsf(acn - (float)(n+1)*Ac0) <= 1e-4f*fabsf(acn));
                } } }
        }
        float s[16];
        #pragma unroll
        for (int n = 0; n < 16; ++n) s[n] = 0.f;
        float Sdt = 0.f;
        if (fastp) {
            for (int t = 0; t < CLEN; ++t) {
                const f32x4* xr = (const f32x4*)&xd_h[0][t * 68];
                f32x4 x0 = xr[0], x1 = xr[1], x2 = xr[2], x3 = xr[3];
                float acc = dtbv;
                #pragma unroll
                for (int j = 0; j < 4; ++j) acc = fmaf(x0[j], dw0[j], acc);
                #pragma unroll
                for (int j = 0; j < 4; ++j) acc = fmaf(x1[j], dw1[j], acc);
                #pragma unroll
                for (int j = 0; j < 4; ++j) acc = fmaf(x2[j], dw2[j], acc);
                #pragma unroll
                for (int j = 0; j < 4; ++j) acc = fmaf(x3[j], dw3[j], acc);
                float dtraw = (acc > 20.0f) ? acc : logf(1.0f + __expf(acc));
                u16 dtu = f2bfu(dtraw);
                dxc[(size_t)(bl0 + t) * DI + d] = ((u32)dtu << 16) | (u32)vb[t];
                float dtv = bfu2f(dtu);
                float dx = dtv * bfu2f(vb[t]);
                Sdt += dtv;
                float e1 = __expf(dtv * Ac0);
                float an[16];
                POW_TREE(an, e1)
                f32x4 b0 = xr[4], b1 = xr[5], b2 = xr[6], b3 = xr[7];
                #pragma unroll
                for (int j = 0; j < 4; ++j) {
                    s[j]    = fmaf(an[j],    s[j],    b0[j] * dx);
                    s[4+j]  = fmaf(an[4+j],  s[4+j],  b1[j] * dx);
                    s[8+j]  = fmaf(an[8+j],  s[8+j],  b2[j] * dx);
                    s[12+j] = fmaf(an[12+j], s[12+j], b3[j] * dx);
                }
            }
        } else {
            for (int t = 0; t < CLEN; ++t) {
                const f32x4* xr = (const f32x4*)&xd_h[0][t * 68];
                f32x4 x0 = xr[0], x1 = xr[1], x2 = xr[2], x3 = xr[3];
                float acc = dtbv;
                #pragma unroll
                for (int j = 0; j < 4; ++j) acc = fmaf(x0[j], dw0[j], acc);
                #pragma unroll
                for (int j = 0; j < 4; ++j) acc = fmaf(x1[j], dw1[j], acc);
                #pragma unroll
                for (int j = 0; j < 4; ++j) acc = fmaf(x2[j], dw2[j], acc);
                #pragma unroll
                for (int j = 0; j < 4; ++j) acc = fmaf(x3[j], dw3[j], acc);
                float dtraw = (acc > 20.0f) ? acc : logf(1.0f + __expf(acc));
                u16 dtu = f2bfu(dtraw);
                dxc[(size_t)(bl0 + t) * DI + d] = ((u32)dtu << 16) | (u32)vb[t];
                float dtv = bfu2f(dtu);
                float dx = dtv * bfu2f(vb[t]);
                Sdt += dtv;
                f32x4 b0 = xr[4], b1 = xr[5], b2 = xr[6], b3 = xr[7];
                #pragma unroll
                for (int n = 0; n < 16; ++n) {
                    float an = __expf(dtv * -__expf(Alog[(size_t)d*16 + n]));
                    float bv = (n < 4) ? b0[n] : (n < 8) ? b1[n-4] : (n < 12) ? b2[n-8] : b3[n-12];
                    s[n] = fmaf(an, s[n], bv * dx);
                }
            }
        }
        float pw[16];
        if (fastp) {
            float E1 = __expf(Ac0 * Sdt);
            POW_TREE(pw, E1)
        } else {
            #pragma unroll
            for (int n = 0; n < 16; ++n)
                pw[n] = __expf(-__expf(Alog[(size_t)d*16 + n]) * Sdt);
        }
        size_t base = ((size_t)flat * DI + d) * 16;
        u16x8 pv0, pv1, sv0, sv1;
        #pragma unroll
        for (int n = 0; n < 8; ++n) {
            pv0[n] = f2bfu(pw[n]);  pv1[n] = f2bfu(pw[8+n]);
            sv0[n] = f2bfu(s[n]);   sv1[n] = f2bfu(s[8+n]);
        }
        *(u16x8*)(Pb + base)     = pv0;  *(u16x8*)(Pb + base + 8) = pv1;
        *(u16x8*)(Sb + base)     = sv0;  *(u16x8*)(Sb + base + 8) = sv1;
    }
}

/* ---------------- scan12: merged superchunk scan + entry states (R7-verified) */
__global__ __launch_bounds__(1024) void scan12_k(
    const u16* __restrict__ Pb, const u16* __restrict__ Sb,
    u16* __restrict__ Hg) {
    __shared__ float pag[NSC][64], sag[NSC][64];
    int tid = threadIdx.x;
    int eo = tid & 63, sc = tid >> 6;
    int elow = blockIdx.x * 64 + eo;
    int b = blockIdx.y;
    int cbase = b * NCH + sc * 16;
    float Pr[16], Sr[16];
    float h = 0.f, p = 1.f;
    #pragma unroll
    for (int k = 0; k < 16; ++k) {
        size_t a = (size_t)(cbase + k) * 8192 + elow;
        Pr[k] = bfu2f(Pb[a]); Sr[k] = bfu2f(Sb[a]);
        h = fmaf(Pr[k], h, Sr[k]);
        p *= Pr[k];
    }
    pag[sc][eo] = p; sag[sc][eo] = h;
    __syncthreads();
    float hs = 0.f;
    for (int s2 = 0; s2 < sc; ++s2)            /* sc uniform per wave */
        hs = fmaf(pag[s2][eo], hs, sag[s2][eo]);
    #pragma unroll
    for (int k = 0; k < 16; ++k) {
        size_t a = (size_t)(cbase + k) * 8192 + elow;
        Hg[a] = f2bfu(hs);
        hs = fmaf(Pr[k], hs, Sr[k]);
    }
}

/* ---------------- fused C: scan replay -> y slab (LDS) -> out_proj MFMA ------- */
/* R6 structure; BCs reads vectorized to ds_read_b128; packed dxc input.        */
__global__ __launch_bounds__(512, 4) void fused_c_k(
    const u32* __restrict__ dxc, const float* __restrict__ BCg,
    const u16* __restrict__ Hg,
    const float* __restrict__ Alog, const float* __restrict__ Dp,
    const u16* __restrict__ xz, const __bf16* __restrict__ outw,
    u16* __restrict__ Ob, float* __restrict__ Of) {
    __shared__ u16 y_s[CLEN * XCP];                                 /* 16.6 KB */
    __shared__ __attribute__((aligned(16))) float BCs[CLEN * 32];   /* 2 KB */
    int tid = threadIdx.x;
    int c = blockIdx.x, b = blockIdx.y;
    int flat = b * NCH + c;
    int bl0 = b * LSEQ + c * CLEN;
    int d = tid;

    BCs[tid] = BCg[(size_t)flat * (CLEN*32) + tid];

    float Ac0; bool fastp = true;
    {
        const f32x4* a4 = (const f32x4*)(Alog + (size_t)d * 16);
        f32x4 v0 = a4[0];
        Ac0 = -__expf(v0[0]);
        #pragma unroll
        for (int g = 0; g < 4; ++g) { f32x4 v = a4[g];
            #pragma unroll
            for (int j = 0; j < 4; ++j) { int n = g*4 + j; if (n) {
                float acn = -__expf(v[j]);
                fastp = fastp && (fabsf(acn - (float)(n+1)*Ac0) <= 1e-4f*fabsf(acn));
            } } }
    }
    float h[16];
    {
        const u16* h8 = Hg + ((size_t)flat * DI + d) * 16;
        u16x8 hv0 = *(const u16x8*)h8;
        u16x8 hv1 = *(const u16x8*)(h8 + 8);
        #pragma unroll
        for (int n = 0; n < 8; ++n) { h[n] = bfu2f(hv0[n]); h[8+n] = bfu2f(hv1[n]); }
    }
    float Dv = Dp[d];
    __syncthreads();

    if (fastp) {
        for (int t = 0; t < CLEN; ++t) {
            u32 dxv = dxc[(size_t)(bl0 + t) * DI + d];
            float dtv = bfu2f((u16)(dxv >> 16));
            float xv  = bfu2f((u16)(dxv & 0xffffu));
            float gv  = bfu2f(xz[(size_t)(bl0 + t) * 1024 + DI + d]);
            float dx = dtv * xv;
            const f32x4* br = (const f32x4*)&BCs[t * 32];
            f32x4 b0 = br[0], b1 = br[1], b2 = br[2], b3 = br[3];
            f32x4 c0 = br[4], c1 = br[5], c2 = br[6], c3 = br[7];
            float e1 = __expf(dtv * Ac0);
            float an[16];
            POW_TREE(an, e1)
            float y0 = 0.f, y1 = 0.f, y2 = 0.f, y3 = 0.f;
            #pragma unroll
            for (int j = 0; j < 4; ++j) {
                h[j]    = fmaf(an[j],    h[j],    b0[j] * dx);
                h[4+j]  = fmaf(an[4+j],  h[4+j],  b1[j] * dx);
                h[8+j]  = fmaf(an[8+j],  h[8+j],  b2[j] * dx);
                h[12+j] = fmaf(an[12+j], h[12+j], b3[j] * dx);
                y0 = fmaf(h[j],    c0[j], y0);
                y1 = fmaf(h[4+j],  c1[j], y1);
                y2 = fmaf(h[8+j],  c2[j], y2);
                y3 = fmaf(h[12+j], c3[j], y3);
            }
            float y = (y0 + y1) + (y2 + y3);
            float yv = fmaf(xv, Dv, y) * siluf(gv);
            y_s[t * XCP + d] = f2bfu(yv);
        }
    } else {
        for (int t = 0; t < CLEN; ++t) {
            u32 dxv = dxc[(size_t)(bl0 + t) * DI + d];
            float dtv = bfu2f((u16)(dxv >> 16));
            float xv  = bfu2f((u16)(dxv & 0xffffu));
            float gv  = bfu2f(xz[(size_t)(bl0 + t) * 1024 + DI + d]);
            float dx = dtv * xv;
            float y = 0.f;
            #pragma unroll
            for (int n = 0; n < 16; ++n) {
                float an = __expf(dtv * -__expf(Alog[(size_t)d*16 + n]));
                h[n] = fmaf(an, h[n], BCs[t*32 + n] * dx);
                y = fmaf(h[n], BCs[t*32 + 16 + n], y);
            }
            float yv = fmaf(xv, Dv, y) * siluf(gv);
            y_s[t * XCP + d] = f2bfu(yv);
        }
    }
    __syncthreads();

    /* out_proj: O[16,256] = y_s[16,512] @ outw[256,512]^T; 8 waves x 2 N-tiles */
    {
        int wave = tid >> 6, lane = tid & 63;
        int row = lane & 15, q = lane >> 4;
        f32x4 acc[2] = {};
        #pragma unroll
        for (int kb = 0; kb < 16; ++kb) {
            bf16x8 a = *(const bf16x8*)&y_s[row * XCP + kb*32 + q*8];
            #pragma unroll
            for (int ni = 0; ni < 2; ++ni) {
                bf16x8 bb = *(const bf16x8*)(outw +
                    (size_t)(wave*32 + ni*16 + row) * 512 + kb*32 + q*8);
                acc[ni] = __builtin_amdgcn_mfma_f32_16x16x32_bf16(a, bb, acc[ni], 0, 0, 0);
            }
        }
        #pragma unroll
        for (int r = 0; r < 4; ++r) {
            size_t gr = (size_t)(bl0 + q*4 + r) * DM;
            #pragma unroll
            for (int ni = 0; ni < 2; ++ni) {
                int gc = wave*32 + ni*16 + row;
                if (Ob) Ob[gr + gc] = f2bfu(acc[ni][r]);
                else    Of[gr + gc] = acc[ni][r];
            }
        }
    }
}

/* ================================================================== */
extern "C" void kernel_launch(void* const* d_in, const int* in_sizes, int n_in,
                              void* d_out, int out_size, void* d_ws, size_t ws_size,
                              hipStream_t stream) {
    (void)in_sizes; (void)n_in; (void)out_size; (void)ws_size;
    const float* z_in   = (const float*)d_in[0];
    const float* in_w   = (const float*)d_in[1];
    const float* conv_w = (const float*)d_in[2];
    const float* conv_b = (const float*)d_in[3];
    const float* xp_w   = (const float*)d_in[4];
    const float* dt_w   = (const float*)d_in[5];
    const float* dt_b   = (const float*)d_in[6];
    const float* A_log  = (const float*)d_in[7];
    const float* D_par  = (const float*)d_in[8];
    const float* out_w  = (const float*)d_in[9];
    float* outp = (float*)d_out;

    char* p = (char*)d_ws;
    auto alloc = [&](size_t bytes) { char* r = p; p += (bytes + 255) & ~(size_t)255; return r; };
    u16* z_bf    = (u16*)alloc((size_t)BLROWS*DM*2);
    u16* z2_bf   = (u16*)alloc((size_t)BLROWS*DM*2);
    u16* xz_bf   = (u16*)alloc((size_t)BLROWS*1024*2);
    u32* dxc_bf  = (u32*)alloc((size_t)BLROWS*DI*4);
    u16* inw_bf  = (u16*)alloc((size_t)2*1024*256*2);
    u16* outw_bf = (u16*)alloc((size_t)2*256*512*2);
    u16* xpw_bf  = (u16*)alloc((size_t)2*64*512*2);
    float* BCg   = (float*)alloc((size_t)BATCH*NCH*CLEN*32*4);
    u16* Pbuf    = (u16*)alloc((size_t)BATCH*NCH*DI*DS*2);
    u16* Sbuf    = (u16*)alloc((size_t)BATCH*NCH*DI*DS*2);
    u16* Hbuf    = (u16*)alloc((size_t)BATCH*NCH*DI*DS*2);

    cast_all_k<<<(N_INW + N_OUTW + N_XPW + N_Z)/256, 256, 0, stream>>>(
        in_w, out_w, xp_w, z_in, inw_bf, outw_bf, xpw_bf, z_bf);

    const u16* zcur = z_bf;
    for (int l = 0; l < 2; ++l) {
        gemm_in_k<<<dim3(BLROWS/128, 1024/128), 256, 0, stream>>>(
            (const __bf16*)zcur, (const __bf16*)(inw_bf + (size_t)l*1024*256),
            xz_bf, BLROWS, 1024, 256);
        fused_a_k<<<dim3(NCH, BATCH), 512, 0, stream>>>(
            xz_bf, conv_w + (size_t)l*DI*4, conv_b + (size_t)l*DI,
            (const __bf16*)(xpw_bf + (size_t)l*64*512),
            dt_w + (size_t)l*DI*16, dt_b + (size_t)l*DI,
            A_log + (size_t)l*DI*DS,
            dxc_bf, BCg, Pbuf, Sbuf);
        scan12_k<<<dim3(8192/64, BATCH), 1024, 0, stream>>>(Pbuf, Sbuf, Hbuf);
        fused_c_k<<<dim3(NCH, BATCH), 512, 0, stream>>>(
            dxc_bf, BCg, Hbuf,
            A_log + (size_t)l*DI*DS, D_par + (size_t)l*DI,
            xz_bf, (const __bf16*)(outw_bf + (size_t)l*256*512),
            (l == 0) ? z2_bf : nullptr, (l == 1) ? outp : nullptr);
        zcur = z2_bf;
    }
}

// Round 11
// 221.942 us; speedup vs baseline: 3.6437x; 1.3911x over previous
//
#include <hip/hip_runtime.h>
#include <hip/hip_bf16.h>
#include <cstdint>
#include <cstddef>

#define DM   256
#define DI   512
#define DS   16
#define LSEQ 4096
#define BATCH 2
#define BLROWS (BATCH * LSEQ)   /* 8192 */
#define NCH  256                /* chunks per sequence */
#define CLEN 16                 /* steps per chunk */
#define NSC  16                 /* superchunks per sequence (16 chunks each) */
#define XCP  520                /* padded LDS row stride (u16) for MFMA A reads */

typedef __bf16 bf16x8 __attribute__((ext_vector_type(8)));
typedef float  f32x4  __attribute__((ext_vector_type(4)));
typedef unsigned short u16;
typedef u16 u16x8 __attribute__((ext_vector_type(8)));

__device__ __forceinline__ u16 f2bfu(float f) {
    union { float f; unsigned u; } c; c.f = f;
    unsigned u = c.u;
    return (u16)((u + 0x7fffu + ((u >> 16) & 1u)) >> 16);
}
__device__ __forceinline__ float bfu2f(u16 u) {
    union { unsigned u; float f; } c; c.u = ((unsigned)u) << 16; return c.f;
}
__device__ __forceinline__ float siluf(float v) {
    return v * (1.0f / (1.0f + __expf(-v)));
}
__device__ __forceinline__ void gload_lds16(const void* g, void* l) {
    __builtin_amdgcn_global_load_lds(
        (const __attribute__((address_space(1))) unsigned int*)g,
        (__attribute__((address_space(3))) unsigned int*)l, 16, 0, 0);
}

/* ---------------- merged startup casts ---------------- */
#define N_INW  (2*1024*256)
#define N_OUTW (2*256*512)
#define N_XPW  (2*64*512)
#define N_Z    (BLROWS*DM)
__global__ __launch_bounds__(256) void cast_all_k(
    const float* __restrict__ in_w, const float* __restrict__ out_w,
    const float* __restrict__ xp_w, const float* __restrict__ z,
    u16* __restrict__ inw_bf, u16* __restrict__ outw_bf,
    u16* __restrict__ xpw_bf, u16* __restrict__ z_bf) {
    int i = blockIdx.x * 256 + threadIdx.x;
    if (i < N_INW) {
        inw_bf[i] = f2bfu(in_w[i]);
    } else if (i < N_INW + N_OUTW) {
        int j = i - N_INW;
        outw_bf[j] = f2bfu(out_w[j]);
    } else if (i < N_INW + N_OUTW + N_XPW) {
        int j = i - (N_INW + N_OUTW);
        int k = j & 511, o = (j >> 9) & 63, l = j >> 15;
        xpw_bf[j] = f2bfu((o < 48) ? xp_w[(l * 48 + o) * 512 + k] : 0.0f);
    } else {
        int j = i - (N_INW + N_OUTW + N_XPW);
        z_bf[j] = f2bfu(z[j]);
    }
}

/* ---------------- in_proj: LDS-staged bf16 MFMA GEMM (m97 pattern) ------------ */
__global__ __launch_bounds__(256) void gemm_in_k(
    const __bf16* __restrict__ A, const __bf16* __restrict__ B,
    u16* __restrict__ Cb, int M, int N, int K) {
    __shared__ __bf16 As[128 * 32];
    __shared__ __bf16 Bs[128 * 32];
    int tid = threadIdx.x, wave = tid >> 6, lane = tid & 63;
    int bm = blockIdx.x * 128, bn = blockIdx.y * 128;
    int wm = (wave & 1) * 64, wn = (wave >> 1) * 64;
    int row = lane & 15, q = lane >> 4;
    int srow = lane >> 2, sseg = lane & 3;
    f32x4 acc[4][4] = {};
    for (int k0 = 0; k0 < K; k0 += 32) {
        #pragma unroll
        for (int i = 0; i < 2; ++i) {
            int r0 = wave * 32 + i * 16;
            gload_lds16(A + (size_t)(bm + r0 + srow) * K + k0 + sseg * 8, As + r0 * 32);
            gload_lds16(B + (size_t)(bn + r0 + srow) * K + k0 + sseg * 8, Bs + r0 * 32);
        }
        __syncthreads();
        bf16x8 af[4], bfr[4];
        #pragma unroll
        for (int mi = 0; mi < 4; ++mi)
            af[mi] = *(const bf16x8*)&As[(wm + mi*16 + row) * 32 + q * 8];
        #pragma unroll
        for (int ni = 0; ni < 4; ++ni)
            bfr[ni] = *(const bf16x8*)&Bs[(wn + ni*16 + row) * 32 + q * 8];
        #pragma unroll
        for (int mi = 0; mi < 4; ++mi)
            #pragma unroll
            for (int ni = 0; ni < 4; ++ni)
                acc[mi][ni] = __builtin_amdgcn_mfma_f32_16x16x32_bf16(
                    af[mi], bfr[ni], acc[mi][ni], 0, 0, 0);
        __syncthreads();
    }
    #pragma unroll
    for (int mi = 0; mi < 4; ++mi)
        #pragma unroll
        for (int r = 0; r < 4; ++r) {
            size_t gr = (size_t)(bm + wm + mi*16 + q*4 + r) * N;
            #pragma unroll
            for (int ni = 0; ni < 4; ++ni)
                Cb[gr + bn + wn + ni*16 + row] = f2bfu(acc[mi][ni][r]);
        }
}

/* ---------------- fused A: conv+silu -> x_proj MFMA -> dt -> chunk scan ------- */
/* grid (NCH, BATCH) = 512 blocks, 512 threads -> 2 blocks/CU, 4 waves/SIMD.    */
__global__ __launch_bounds__(512, 4) void fused_a_k(
    const u16* __restrict__ xz, const float* __restrict__ cw,
    const float* __restrict__ cb, const __bf16* __restrict__ xpw,
    const float* __restrict__ dtw, const float* __restrict__ dtb,
    const float* __restrict__ Alog,
    u16* __restrict__ xcb, u16* __restrict__ dtob,
    float* __restrict__ BCg, u16* __restrict__ Pb, u16* __restrict__ Sb) {
    __shared__ u16 xc_s[CLEN * XCP];       /* 16.6 KB */
    __shared__ float xd_h[2][CLEN * 68];   /* 8.7 KB: K-split partials, summed into [0] */
    int tid = threadIdx.x;
    int c = blockIdx.x, b = blockIdx.y;
    int flat = b * NCH + c;
    int bl0 = b * LSEQ + c * CLEN;
    int d = tid;

    /* phase 1: causal depthwise conv + bias + silu (thread = channel) */
    {
        float w0 = cw[d*4], w1 = cw[d*4+1], w2 = cw[d*4+2], w3 = cw[d*4+3];
        float bias = cb[d];
        float xm3 = 0.f, xm2 = 0.f, xm1 = 0.f;
        int l0 = c * CLEN;
        if (l0 - 3 >= 0) xm3 = bfu2f(xz[(size_t)(bl0 - 3) * 1024 + d]);
        if (l0 - 2 >= 0) xm2 = bfu2f(xz[(size_t)(bl0 - 2) * 1024 + d]);
        if (l0 - 1 >= 0) xm1 = bfu2f(xz[(size_t)(bl0 - 1) * 1024 + d]);
        #pragma unroll 4
        for (int t = 0; t < CLEN; ++t) {
            float xcur = bfu2f(xz[(size_t)(bl0 + t) * 1024 + d]);
            float acc = fmaf(w0, xm3, fmaf(w1, xm2, fmaf(w2, xm1, fmaf(w3, xcur, bias))));
            float v = siluf(acc);
            u16 vb = f2bfu(v);
            xc_s[t * XCP + d] = vb;
            xcb[(size_t)(bl0 + t) * DI + d] = vb;
            xm3 = xm2; xm2 = xm1; xm1 = xcur;
        }
    }
    __syncthreads();

    /* phase 2: x_proj  xd[16,64] = xc_s[16,512] @ xpw[64,512]^T.
       8 waves: nt = wave&3 (N-tile), kh = wave>>2 (K half), LDS-summed. */
    {
        int wave = tid >> 6, lane = tid & 63;
        int row = lane & 15, q = lane >> 4;
        int nt = wave & 3, kh = wave >> 2;
        f32x4 acc = {0.f, 0.f, 0.f, 0.f};
        #pragma unroll
        for (int kb = 0; kb < 8; ++kb) {
            int kk = (kh*8 + kb) * 32;
            bf16x8 a = *(const bf16x8*)&xc_s[row * XCP + kk + q*8];
            bf16x8 bb = *(const bf16x8*)(xpw + (size_t)(nt*16 + row) * 512 + kk + q*8);
            acc = __builtin_amdgcn_mfma_f32_16x16x32_bf16(a, bb, acc, 0, 0, 0);
        }
        #pragma unroll
        for (int r = 0; r < 4; ++r)
            xd_h[kh][(q*4 + r) * 68 + nt*16 + row] = acc[r];
    }
    __syncthreads();
    for (int j = tid; j < CLEN * 68; j += 512) xd_h[0][j] += xd_h[1][j];
    __syncthreads();

    /* store compact B,C (cols 16..47) for fused_c; one elem per thread */
    {
        int t = tid >> 5, cc = tid & 31;
        BCg[(size_t)flat * (CLEN*32) + tid] = xd_h[0][t*68 + 16 + cc];
    }

    /* phase 3: dt = softplus(xd[:, :16] @ dtw^T + dtb); chunk scan -> P,S */
    {
        float dtwr[16];
        const f32x4* w4 = (const f32x4*)(dtw + (size_t)d * 16);
        #pragma unroll
        for (int g = 0; g < 4; ++g) { f32x4 v = w4[g];
            dtwr[g*4] = v[0]; dtwr[g*4+1] = v[1]; dtwr[g*4+2] = v[2]; dtwr[g*4+3] = v[3]; }
        float dtbv = dtb[d];
        float Ac[16];
        const f32x4* a4 = (const f32x4*)(Alog + (size_t)d * 16);
        #pragma unroll
        for (int g = 0; g < 4; ++g) { f32x4 v = a4[g];
            #pragma unroll
            for (int j = 0; j < 4; ++j) Ac[g*4+j] = -__expf(v[j]); }
        bool fastp = true;
        #pragma unroll
        for (int n = 1; n < 16; ++n)
            fastp = fastp && (fabsf(Ac[n] - (float)(n+1) * Ac[0])
                              <= 1e-4f * fabsf(Ac[n]));
        float p[16], s[16];
        #pragma unroll
        for (int n = 0; n < 16; ++n) { p[n] = 1.0f; s[n] = 0.0f; }
        for (int t = 0; t < CLEN; ++t) {
            float acc = dtbv;
            #pragma unroll
            for (int r = 0; r < 16; ++r) acc = fmaf(xd_h[0][t*68 + r], dtwr[r], acc);
            float dtraw = (acc > 20.0f) ? acc : logf(1.0f + __expf(acc));
            float dtv = bfu2f(f2bfu(dtraw));
            dtob[(size_t)(bl0 + t) * DI + d] = f2bfu(dtraw);
            float xv = bfu2f(xc_s[t * XCP + d]);
            float dx = dtv * xv;
            float an[16];
            if (fastp) {
                float a0 = __expf(dtv * Ac[0]);
                an[0] = a0;
                #pragma unroll
                for (int n = 1; n < 16; ++n) an[n] = an[n-1] * a0;
            } else {
                #pragma unroll
                for (int n = 0; n < 16; ++n) an[n] = __expf(dtv * Ac[n]);
            }
            #pragma unroll
            for (int n = 0; n < 16; ++n) {
                s[n] = fmaf(an[n], s[n], xd_h[0][t*68 + 16 + n] * dx);
                p[n] *= an[n];
            }
        }
        size_t base = ((size_t)flat * DI + d) * 16;
        u16x8 pv0, pv1, sv0, sv1;
        #pragma unroll
        for (int n = 0; n < 8; ++n) {
            pv0[n] = f2bfu(p[n]);   pv1[n] = f2bfu(p[8+n]);
            sv0[n] = f2bfu(s[n]);   sv1[n] = f2bfu(s[8+n]);
        }
        *(u16x8*)(Pb + base)     = pv0;  *(u16x8*)(Pb + base + 8) = pv1;
        *(u16x8*)(Sb + base)     = sv0;  *(u16x8*)(Sb + base + 8) = sv1;
    }
}

/* ---------------- scan12: merged superchunk scan + entry states -------------- */
/* block = 1024 thr = 16 sc x 64 elow; aggregates exchanged via LDS;
   P/S kept in regs for replay.  grid (8192/64, BATCH).  f32 Hg (R3-compatible). */
__global__ __launch_bounds__(1024) void scan12_k(
    const u16* __restrict__ Pb, const u16* __restrict__ Sb,
    float* __restrict__ Hg) {
    __shared__ float pag[NSC][64], sag[NSC][64];
    int tid = threadIdx.x;
    int eo = tid & 63, sc = tid >> 6;
    int elow = blockIdx.x * 64 + eo;
    int b = blockIdx.y;
    int cbase = b * NCH + sc * 16;
    float Pr[16], Sr[16];
    float h = 0.f, p = 1.f;
    #pragma unroll
    for (int k = 0; k < 16; ++k) {
        size_t a = (size_t)(cbase + k) * 8192 + elow;
        Pr[k] = bfu2f(Pb[a]); Sr[k] = bfu2f(Sb[a]);
        h = fmaf(Pr[k], h, Sr[k]);
        p *= Pr[k];
    }
    pag[sc][eo] = p; sag[sc][eo] = h;
    __syncthreads();
    float hs = 0.f;
    for (int s2 = 0; s2 < sc; ++s2)            /* sc uniform per wave */
        hs = fmaf(pag[s2][eo], hs, sag[s2][eo]);
    #pragma unroll
    for (int k = 0; k < 16; ++k) {
        size_t a = (size_t)(cbase + k) * 8192 + elow;
        Hg[a] = hs;
        hs = fmaf(Pr[k], hs, Sr[k]);
    }
}

/* ---------------- fused C: scan replay -> y slab (LDS) -> out_proj MFMA ------- */
__global__ __launch_bounds__(512, 4) void fused_c_k(
    const u16* __restrict__ xcb, const u16* __restrict__ dtob,
    const float* __restrict__ BCg, const float* __restrict__ Hg,
    const float* __restrict__ Alog, const float* __restrict__ Dp,
    const u16* __restrict__ xz, const __bf16* __restrict__ outw,
    u16* __restrict__ Ob, float* __restrict__ Of) {
    __shared__ u16 y_s[CLEN * XCP];        /* 16.6 KB */
    __shared__ float BCs[CLEN * 32];       /* 2 KB */
    int tid = threadIdx.x;
    int c = blockIdx.x, b = blockIdx.y;
    int flat = b * NCH + c;
    int bl0 = b * LSEQ + c * CLEN;
    int d = tid;

    BCs[tid] = BCg[(size_t)flat * (CLEN*32) + tid];

    float Ac[16], h[16];
    {
        const f32x4* a4 = (const f32x4*)(Alog + (size_t)d * 16);
        const f32x4* h4 = (const f32x4*)(Hg + ((size_t)flat * DI + d) * 16);
        #pragma unroll
        for (int g = 0; g < 4; ++g) {
            f32x4 av = a4[g]; f32x4 hv = h4[g];
            #pragma unroll
            for (int j = 0; j < 4; ++j) { Ac[g*4+j] = -__expf(av[j]); h[g*4+j] = hv[j]; }
        }
    }
    bool fastp = true;
    #pragma unroll
    for (int n = 1; n < 16; ++n)
        fastp = fastp && (fabsf(Ac[n] - (float)(n+1) * Ac[0]) <= 1e-4f * fabsf(Ac[n]));
    float Dv = Dp[d];
    __syncthreads();

    #pragma unroll 4
    for (int t = 0; t < CLEN; ++t) {
        float dtv = bfu2f(dtob[(size_t)(bl0 + t) * DI + d]);
        float xv  = bfu2f(xcb[(size_t)(bl0 + t) * DI + d]);
        float gv  = bfu2f(xz[(size_t)(bl0 + t) * 1024 + DI + d]);
        float dx = dtv * xv;
        float an[16];
        if (fastp) {
            float a0 = __expf(dtv * Ac[0]);
            an[0] = a0;
            #pragma unroll
            for (int n = 1; n < 16; ++n) an[n] = an[n-1] * a0;
        } else {
            #pragma unroll
            for (int n = 0; n < 16; ++n) an[n] = __expf(dtv * Ac[n]);
        }
        float y = 0.f;
        #pragma unroll
        for (int n = 0; n < 16; ++n) {
            h[n] = fmaf(an[n], h[n], BCs[t*32 + n] * dx);
            y = fmaf(h[n], BCs[t*32 + 16 + n], y);
        }
        float yv = fmaf(xv, Dv, y) * siluf(gv);
        y_s[t * XCP + d] = f2bfu(yv);
    }
    __syncthreads();

    /* out_proj: O[16,256] = y_s[16,512] @ outw[256,512]^T; 8 waves x 2 N-tiles */
    {
        int wave = tid >> 6, lane = tid & 63;
        int row = lane & 15, q = lane >> 4;
        f32x4 acc[2] = {};
        #pragma unroll
        for (int kb = 0; kb < 16; ++kb) {
            bf16x8 a = *(const bf16x8*)&y_s[row * XCP + kb*32 + q*8];
            #pragma unroll
            for (int ni = 0; ni < 2; ++ni) {
                bf16x8 bb = *(const bf16x8*)(outw +
                    (size_t)(wave*32 + ni*16 + row) * 512 + kb*32 + q*8);
                acc[ni] = __builtin_amdgcn_mfma_f32_16x16x32_bf16(a, bb, acc[ni], 0, 0, 0);
            }
        }
        #pragma unroll
        for (int r = 0; r < 4; ++r) {
            size_t gr = (size_t)(bl0 + q*4 + r) * DM;
            #pragma unroll
            for (int ni = 0; ni < 2; ++ni) {
                int gc = wave*32 + ni*16 + row;
                if (Ob) Ob[gr + gc] = f2bfu(acc[ni][r]);
                else    Of[gr + gc] = acc[ni][r];
            }
        }
    }
}

/* ================================================================== */
extern "C" void kernel_launch(void* const* d_in, const int* in_sizes, int n_in,
                              void* d_out, int out_size, void* d_ws, size_t ws_size,
                              hipStream_t stream) {
    (void)in_sizes; (void)n_in; (void)out_size; (void)ws_size;
    const float* z_in   = (const float*)d_in[0];
    const float* in_w   = (const float*)d_in[1];
    const float* conv_w = (const float*)d_in[2];
    const float* conv_b = (const float*)d_in[3];
    const float* xp_w   = (const float*)d_in[4];
    const float* dt_w   = (const float*)d_in[5];
    const float* dt_b   = (const float*)d_in[6];
    const float* A_log  = (const float*)d_in[7];
    const float* D_par  = (const float*)d_in[8];
    const float* out_w  = (const float*)d_in[9];
    float* outp = (float*)d_out;

    char* p = (char*)d_ws;
    auto alloc = [&](size_t bytes) { char* r = p; p += (bytes + 255) & ~(size_t)255; return r; };
    u16* z_bf    = (u16*)alloc((size_t)BLROWS*DM*2);
    u16* z2_bf   = (u16*)alloc((size_t)BLROWS*DM*2);
    u16* xz_bf   = (u16*)alloc((size_t)BLROWS*1024*2);
    u16* xc_bf   = (u16*)alloc((size_t)BLROWS*DI*2);
    u16* dt_bf   = (u16*)alloc((size_t)BLROWS*DI*2);
    u16* inw_bf  = (u16*)alloc((size_t)2*1024*256*2);
    u16* outw_bf = (u16*)alloc((size_t)2*256*512*2);
    u16* xpw_bf  = (u16*)alloc((size_t)2*64*512*2);
    float* BCg   = (float*)alloc((size_t)BATCH*NCH*CLEN*32*4);
    u16* Pbuf    = (u16*)alloc((size_t)BATCH*NCH*DI*DS*2);
    u16* Sbuf    = (u16*)alloc((size_t)BATCH*NCH*DI*DS*2);
    float* Hbuf  = (float*)alloc((size_t)BATCH*NCH*DI*DS*4);

    cast_all_k<<<(N_INW + N_OUTW + N_XPW + N_Z)/256, 256, 0, stream>>>(
        in_w, out_w, xp_w, z_in, inw_bf, outw_bf, xpw_bf, z_bf);

    const u16* zcur = z_bf;
    for (int l = 0; l < 2; ++l) {
        gemm_in_k<<<dim3(BLROWS/128, 1024/128), 256, 0, stream>>>(
            (const __bf16*)zcur, (const __bf16*)(inw_bf + (size_t)l*1024*256),
            xz_bf, BLROWS, 1024, 256);
        fused_a_k<<<dim3(NCH, BATCH), 512, 0, stream>>>(
            xz_bf, conv_w + (size_t)l*DI*4, conv_b + (size_t)l*DI,
            (const __bf16*)(xpw_bf + (size_t)l*64*512),
            dt_w + (size_t)l*DI*16, dt_b + (size_t)l*DI,
            A_log + (size_t)l*DI*DS,
            xc_bf, dt_bf, BCg, Pbuf, Sbuf);
        scan12_k<<<dim3(8192/64, BATCH), 1024, 0, stream>>>(Pbuf, Sbuf, Hbuf);
        fused_c_k<<<dim3(NCH, BATCH), 512, 0, stream>>>(
            xc_bf, dt_bf, BCg, Hbuf,
            A_log + (size_t)l*DI*DS, D_par + (size_t)l*DI,
            xz_bf, (const __bf16*)(outw_bf + (size_t)l*256*512),
            (l == 0) ? z2_bf : nullptr, (l == 1) ? outp : nullptr);
        zcur = z2_bf;
    }
}